// Round 1
// baseline (109.164 us; speedup 1.0000x reference)
//
#include <hip/hip_runtime.h>

// B=16384, DIM=64, 8 coupling steps, H=8, D2=32.
// y = J^{-1} g applied analytically (triangular coupling blocks -> MLP JVPs);
// intermediate states recovered by inverting the flow from z = phi(x).
//
// R11 = R10 MFMA formulation + occupancy break-out:
//   R10 ran 16 elements/wave -> 1024 waves = 1 wave/SIMD (zero TLP; every
//   latency on the 32-half-step serial chain fully exposed). MFMA columns
//   are independent (D[:,n] = A @ B[:,n]), so R11 runs 8 elements/wave with
//   lanes n>=8 mirroring lane n-8 (identical data, no garbage, no new sync).
//   -> 2048 waves; H-frag cache compacted to active lanes (32 KiB), total
//   LDS 74 KiB -> 2 blocks/CU -> 2 waves/SIMD. Two independent streams per
//   SIMD interleave and hide each other's MFMA/LDS/trans latency.
// Layout identity (gfx950, verified m89): D (col=lane&15,row=4q+reg) ==
// B-operand (n=lane&15,k=4q+j) for K=16 -> tanh(D)->pack is per-lane, zero
// cross-lane ops.

namespace {

typedef __fp16 f16x2 __attribute__((ext_vector_type(2)));
typedef __fp16 v4h __attribute__((ext_vector_type(4)));
typedef __fp16 v8h __attribute__((ext_vector_type(8)));
typedef float f32x4 __attribute__((ext_vector_type(4)));

constexpr int NB = 16384;

__device__ __forceinline__ float frcp(float x) { return __builtin_amdgcn_rcpf(x); }
__device__ __forceinline__ float ftanh(float x) {
  float e = __expf(2.f * x);
  return 1.f - 2.f * frcp(e + 1.f);
}
__device__ __forceinline__ f16x2 pk(float a, float b) {
  return __builtin_amdgcn_cvt_pkrtz(a, b);
}

union U8 { v8h v; f16x2 h[4]; float4 f4; };
union U4 { v4h v; f16x2 h[2]; float2 f2; };

// net pair p (0..15): step i = p>>1, half = p&1 -> t-net base.
__device__ __forceinline__ int pbase(int p) {
  return ((p >> 1) << 2) + ((p & 1) << 1);
}

}  // namespace

// 256 threads = 4 waves = 32 elements/block (8/wave, mirrored), grid 512 ->
// 2048 waves = 2/SIMD, 2 blocks/CU. LDS: 42 KiB weights + 32 KiB H-cache =
// 74 KiB (<80 KiB so two blocks co-reside).
__global__ __launch_bounds__(256, 2) void nf_policy_kernel(
    const float* __restrict__ x, const float* __restrict__ xs,
    const float* __restrict__ gW0, const float* __restrict__ gb0,
    const float* __restrict__ gW1, const float* __restrict__ gb1,
    const float* __restrict__ gW2, const float* __restrict__ gb2,
    float* __restrict__ out) {
  __shared__ __align__(16) f16x2 LW0[4096];  // [16p][4q][16m][4w] A-frags L1
  __shared__ __align__(16) f16x2 LW1[1024];  // [16p][2half][8row][4kk]
  __shared__ __align__(16) f16x2 LW2[4096];  // [16p][4b][16m][4kk(2 used)]
  __shared__ __align__(16) float LB0[256];   // [16p][16m]
  __shared__ __align__(16) float LB1[256];   // [16p][16m]
  __shared__ __align__(16) float LB2[1024];  // [16p][4b][16m]
  __shared__ __align__(16) float4 sHC[2048]; // [16p][128 active ln] H1H2 cache

  const int tid = threadIdx.x;
  // ---- stage weights: fp32 global -> f16 LDS in MFMA A-fragment order ----
  for (int i = tid; i < 4096; i += 256) {  // LW0
    const int p = i >> 8, rem = i & 255, qq = rem >> 6, rem2 = rem & 63;
    const int mm = rem2 >> 2, w = rem2 & 3;
    const int net = pbase(p) + (mm >> 3);
    const int h = mm & 7, k0 = qq * 8 + w * 2;
    const float* src = gW0 + net * 256 + h * 32 + k0;
    LW0[i] = pk(src[0], src[1]);
  }
  for (int i = tid; i < 1024; i += 256) {  // LW1
    const int p = i >> 6, rem = i & 63, half = rem >> 5;
    const int row = (rem >> 2) & 7, kk = rem & 3;
    const int net = pbase(p) + half;
    const float* src = gW1 + net * 64 + row * 8 + kk * 2;
    LW1[i] = pk(src[0], src[1]);
  }
  for (int i = tid; i < 4096; i += 256) {  // LW2 (rows permuted)
    const int p = i >> 8, rem = i & 255, b = rem >> 6, rem2 = rem & 63;
    const int mm = rem2 >> 2, kk = rem2 & 3;
    const int net = pbase(p) + (b >> 1);
    const int d = 8 * (mm >> 2) + ((b & 1) << 2) + (mm & 3);
    const float* src = gW2 + net * 256 + d * 8 + kk * 2;
    LW2[i] = pk(src[0], src[1]);
  }
  for (int i = tid; i < 256; i += 256) {  // LB0/LB1
    const int p = i >> 4, mm = i & 15;
    const int net = pbase(p) + (mm >> 3);
    LB0[i] = gb0[net * 8 + (mm & 7)];
    LB1[i] = gb1[net * 8 + (mm & 7)];
  }
  for (int i = tid; i < 1024; i += 256) {  // LB2 (permuted like LW2 rows)
    const int p = i >> 6, b = (i >> 4) & 3, mm = i & 15;
    const int net = pbase(p) + (b >> 1);
    const int d = 8 * (mm >> 2) + ((b & 1) << 2) + (mm & 3);
    LB2[i] = gb2[net * 32 + d];
  }
  __syncthreads();

  const int lane = tid & 63;
  const int wv = tid >> 6;
  const int n = lane & 15;   // MFMA col / A row role (lanes n>=8 mirror n-8)
  const int q = lane >> 4;   // quad: owns state dims 8q..8q+7
  const int e = blockIdx.x * 32 + wv * 8 + (n & 7);
  const int hcb = wv * 32 + q * 8 + (n & 7);  // compacted H-cache slot

  v4h z4;
#pragma unroll
  for (int jj = 0; jj < 4; ++jj) z4[jj] = (__fp16)0.f;
  const f32x4 zc = {0.f, 0.f, 0.f, 0.f};
  const bool act1 = (n < 8) == (q < 2);
  const int a1off = ((n & 7) << 2) + ((q & 1) << 1) + ((n >= 8) ? 32 : 0);
  const int abbase = n * 4 + ((q & 1) << 1);

  float lo[8], up[8], av[8], bv[8];
  {
    const float* xe = x + (size_t)e * 64;
    const float* se = xs + (size_t)e * 64;
    const float4 a0 = *(const float4*)(xe + q * 8);
    const float4 a1 = *(const float4*)(xe + q * 8 + 4);
    const float4 u0 = *(const float4*)(xe + 32 + q * 8);
    const float4 u1 = *(const float4*)(xe + 32 + q * 8 + 4);
    const float4 p0 = *(const float4*)(se + q * 8);
    const float4 p1 = *(const float4*)(se + q * 8 + 4);
    const float4 r0 = *(const float4*)(se + 32 + q * 8);
    const float4 r1 = *(const float4*)(se + 32 + q * 8 + 4);
    lo[0] = a0.x; lo[1] = a0.y; lo[2] = a0.z; lo[3] = a0.w;
    lo[4] = a1.x; lo[5] = a1.y; lo[6] = a1.z; lo[7] = a1.w;
    up[0] = u0.x; up[1] = u0.y; up[2] = u0.z; up[3] = u0.w;
    up[4] = u1.x; up[5] = u1.y; up[6] = u1.z; up[7] = u1.w;
    av[0] = -2.f * (a0.x - p0.x); av[1] = -2.f * (a0.y - p0.y);
    av[2] = -2.f * (a0.z - p0.z); av[3] = -2.f * (a0.w - p0.w);
    av[4] = -2.f * (a1.x - p1.x); av[5] = -2.f * (a1.y - p1.y);
    av[6] = -2.f * (a1.z - p1.z); av[7] = -2.f * (a1.w - p1.w);
    bv[0] = -2.f * (u0.x - r0.x); bv[1] = -2.f * (u0.y - r0.y);
    bv[2] = -2.f * (u0.z - r0.z); bv[3] = -2.f * (u0.w - r0.w);
    bv[4] = -2.f * (u1.x - r1.x); bv[5] = -2.f * (u1.y - r1.y);
    bv[6] = -2.f * (u1.z - r1.z); bv[7] = -2.f * (u1.w - r1.w);
  }

  float t8[8], s8[8], ut8[8], us8[8];

  // ---------------- forward: z = phi(x); cache H1/H2 frags ---------------
#pragma unroll
  for (int hs = 0; hs < 16; ++hs) {
    const int p = hs;
    float* v = (p & 1) ? up : lo;       // input state of this pair
    float* w = (p & 1) ? lo : up;       // state being updated
    U8 B;
    B.h[0] = pk(v[0], v[1]);
    B.h[1] = pk(v[2], v[3]);
    B.h[2] = pk(v[4], v[5]);
    B.h[3] = pk(v[6], v[7]);
    const v8h A0 = *(const v8h*)(LW0 + ((p * 64 + q * 16 + n) << 2));
    const f32x4 c0 = *(const f32x4*)(LB0 + p * 16 + q * 4);
    f32x4 d1 = __builtin_amdgcn_mfma_f32_16x16x32_f16(A0, B.v, c0, 0, 0, 0);
    float h1[4];
#pragma unroll
    for (int r = 0; r < 4; ++r) h1[r] = ftanh(d1[r]);
    U4 H1;
    H1.h[0] = pk(h1[0], h1[1]);
    H1.h[1] = pk(h1[2], h1[3]);
    v4h A1 = *(const v4h*)(LW1 + (p * 64 + a1off));
    A1 = act1 ? A1 : z4;
    const f32x4 c1 = *(const f32x4*)(LB1 + p * 16 + q * 4);
    f32x4 d2 = __builtin_amdgcn_mfma_f32_16x16x16f16(A1, H1.v, c1, 0, 0, 0);
    float h2[4];
#pragma unroll
    for (int r = 0; r < 4; ++r) h2[r] = ftanh(d2[r]);
    U4 H2;
    H2.h[0] = pk(h2[0], h2[1]);
    H2.h[1] = pk(h2[2], h2[3]);
    // cache both fragments (one b128 store; active lanes only, mirrors skip)
    {
      float4 pkd;
      pkd.x = __builtin_bit_cast(float, H1.h[0]);
      pkd.y = __builtin_bit_cast(float, H1.h[1]);
      pkd.z = __builtin_bit_cast(float, H2.h[0]);
      pkd.w = __builtin_bit_cast(float, H2.h[1]);
      if (n < 8) sHC[p * 128 + hcb] = pkd;
    }
#pragma unroll
    for (int b = 0; b < 4; ++b) {
      const bool act = (b < 2) == (q < 2);
      v4h Ab = *(const v4h*)(LW2 + (p * 256 + b * 64 + abbase));
      Ab = act ? Ab : z4;
      const f32x4 cb = *(const f32x4*)(LB2 + (p * 4 + b) * 16 + q * 4);
      f32x4 ob = __builtin_amdgcn_mfma_f32_16x16x16f16(Ab, H2.v, cb, 0, 0, 0);
      float* dst = (b < 2) ? t8 : s8;
      const int off = (b & 1) * 4;
#pragma unroll
      for (int r = 0; r < 4; ++r) dst[off + r] = ob[r];
    }
#pragma unroll
    for (int j = 0; j < 8; ++j) w[j] = fmaf(w[j], __expf(s8[j]), t8[j]);
  }

  // ------------- backward: y = J^{-1} g, inverting the flow -------------
#pragma unroll
  for (int hs = 15; hs >= 0; --hs) {
    const int p = hs;
    float* st = (p & 1) ? lo : up;      // state updated by this pair in fwd
    float* dme = (p & 1) ? av : bv;     // dual of that state
    float* dot = (p & 1) ? bv : av;     // dual of the pair's input state
    // cached fragments (mirror lanes read their twin's identical slot)
    U4 H1, H2;
    {
      const float4 pkd = sHC[p * 128 + hcb];
      H1.h[0] = __builtin_bit_cast(f16x2, pkd.x);
      H1.h[1] = __builtin_bit_cast(f16x2, pkd.y);
      H2.h[0] = __builtin_bit_cast(f16x2, pkd.z);
      H2.h[1] = __builtin_bit_cast(f16x2, pkd.w);
    }
    // JVP at the dual of the input state
    U8 Bu;
    Bu.h[0] = pk(dot[0], dot[1]);
    Bu.h[1] = pk(dot[2], dot[3]);
    Bu.h[2] = pk(dot[4], dot[5]);
    Bu.h[3] = pk(dot[6], dot[7]);
    const v8h A0 = *(const v8h*)(LW0 + ((p * 64 + q * 16 + n) << 2));
    f32x4 d1u = __builtin_amdgcn_mfma_f32_16x16x32_f16(A0, Bu.v, zc, 0, 0, 0);
    float g1[4];
#pragma unroll
    for (int r = 0; r < 4; ++r) {
      const float h1r = (float)H1.v[r];
      g1[r] = (1.f - h1r * h1r) * d1u[r];
    }
    U4 G1;
    G1.h[0] = pk(g1[0], g1[1]);
    G1.h[1] = pk(g1[2], g1[3]);
    v4h A1 = *(const v4h*)(LW1 + (p * 64 + a1off));
    A1 = act1 ? A1 : z4;
    f32x4 d2u = __builtin_amdgcn_mfma_f32_16x16x16f16(A1, G1.v, zc, 0, 0, 0);
    float g2[4];
#pragma unroll
    for (int r = 0; r < 4; ++r) {
      const float h2r = (float)H2.v[r];
      g2[r] = (1.f - h2r * h2r) * d2u[r];
    }
    U4 G2;
    G2.h[0] = pk(g2[0], g2[1]);
    G2.h[1] = pk(g2[2], g2[3]);
    // L3: t/s recompute (cached H2) + JVP, 8 independent MFMAs
#pragma unroll
    for (int b = 0; b < 4; ++b) {
      const bool act = (b < 2) == (q < 2);
      v4h Ab = *(const v4h*)(LW2 + (p * 256 + b * 64 + abbase));
      Ab = act ? Ab : z4;
      const f32x4 cb = *(const f32x4*)(LB2 + (p * 4 + b) * 16 + q * 4);
      f32x4 ob = __builtin_amdgcn_mfma_f32_16x16x16f16(Ab, H2.v, cb, 0, 0, 0);
      f32x4 jb = __builtin_amdgcn_mfma_f32_16x16x16f16(Ab, G2.v, zc, 0, 0, 0);
      float* dst = (b < 2) ? t8 : s8;
      float* jdst = (b < 2) ? ut8 : us8;
      const int off = (b & 1) * 4;
#pragma unroll
      for (int r = 0; r < 4; ++r) {
        dst[off + r] = ob[r];
        jdst[off + r] = jb[r];
      }
    }
    // invert coupling + dual update
#pragma unroll
    for (int j = 0; j < 8; ++j) {
      const float esi = __expf(-s8[j]);
      const float d = st[j] - t8[j];
      st[j] = d * esi;
      dme[j] = (dme[j] - ut8[j] - d * us8[j]) * esi;
    }
  }

  if (n < 8) {
    float* oe = out + (size_t)e * 64;
    float4 v;
    v.x = av[0]; v.y = av[1]; v.z = av[2]; v.w = av[3];
    *(float4*)(oe + q * 8) = v;
    v.x = av[4]; v.y = av[5]; v.z = av[6]; v.w = av[7];
    *(float4*)(oe + q * 8 + 4) = v;
    v.x = bv[0]; v.y = bv[1]; v.z = bv[2]; v.w = bv[3];
    *(float4*)(oe + 32 + q * 8) = v;
    v.x = bv[4]; v.y = bv[5]; v.z = bv[6]; v.w = bv[7];
    *(float4*)(oe + 32 + q * 8 + 4) = v;
  }
}

extern "C" void kernel_launch(void* const* d_in, const int* in_sizes, int n_in,
                              void* d_out, int out_size, void* d_ws,
                              size_t ws_size, hipStream_t stream) {
  const float* x  = (const float*)d_in[0];
  const float* xs = (const float*)d_in[1];
  const float* W0 = (const float*)d_in[2];
  const float* b0 = (const float*)d_in[3];
  const float* W1 = (const float*)d_in[4];
  const float* b1 = (const float*)d_in[5];
  const float* W2 = (const float*)d_in[6];
  const float* b2 = (const float*)d_in[7];
  float* out = (float*)d_out;

  dim3 grid(NB / 32);  // 512 blocks, 32 elements each (8 per wave, mirrored)
  dim3 block(256);
  nf_policy_kernel<<<grid, block, 0, stream>>>(x, xs, W0, b0, W1, b1, W2, b2,
                                               out);
}

// Round 3
// 106.720 us; speedup vs baseline: 1.0229x; 1.0229x over previous
//
#include <hip/hip_runtime.h>

// B=16384, DIM=64, 8 coupling steps, H=8, D2=32.
// y = J^{-1} g applied analytically (triangular coupling blocks -> MLP JVPs);
// intermediate states recovered by inverting the flow from z = phi(x).
//
// R13 = R12 retry (previous round was an infra failure, no kernel verdict).
//   R11 (8 elem/wave mirrored, 2048 waves, 74 KiB LDS -> 2 blocks/CU) with
//   the register budget FIXED. R11's __launch_bounds__(256,2) is only a
//   floor; the backend targeted 4 waves/EU -> clamped to 128 VGPR and spilled
//   ~25 MB/dispatch of scratch to HBM (WRITE_SIZE 29.6 MB vs 4 MB output),
//   regressing 38->51 us. LDS already caps occupancy at 2 waves/SIMD, so pin
//   amdgpu_waves_per_eu(2,2) + amdgpu_flat_work_group_size(256,256):
//   VGPR budget 256, no spills, full unroll lives in registers.
// Layout identity (gfx950, verified m89): D (col=lane&15,row=4q+reg) ==
// B-operand (n=lane&15,k=4q+j) for K=16 -> tanh(D)->pack is per-lane, zero
// cross-lane ops.

namespace {

typedef __fp16 f16x2 __attribute__((ext_vector_type(2)));
typedef __fp16 v4h __attribute__((ext_vector_type(4)));
typedef __fp16 v8h __attribute__((ext_vector_type(8)));
typedef float f32x4 __attribute__((ext_vector_type(4)));

constexpr int NB = 16384;

__device__ __forceinline__ float frcp(float x) { return __builtin_amdgcn_rcpf(x); }
__device__ __forceinline__ float ftanh(float x) {
  float e = __expf(2.f * x);
  return 1.f - 2.f * frcp(e + 1.f);
}
__device__ __forceinline__ f16x2 pk(float a, float b) {
  return __builtin_amdgcn_cvt_pkrtz(a, b);
}

union U8 { v8h v; f16x2 h[4]; float4 f4; };
union U4 { v4h v; f16x2 h[2]; float2 f2; };

// net pair p (0..15): step i = p>>1, half = p&1 -> t-net base.
__device__ __forceinline__ int pbase(int p) {
  return ((p >> 1) << 2) + ((p & 1) << 1);
}

}  // namespace

// 256 threads = 4 waves = 32 elements/block (8/wave, mirrored), grid 512 ->
// 2048 waves = 2/SIMD, 2 blocks/CU. LDS: 42 KiB weights + 32 KiB H-cache =
// 74 KiB (<80 KiB so two blocks co-reside). waves_per_eu pinned (2,2) so the
// allocator budgets 256 VGPR/wave (the LDS-implied occupancy) and does NOT
// spill to scratch chasing 4 waves/EU it can never have.
__global__ __attribute__((amdgpu_flat_work_group_size(256, 256),
                          amdgpu_waves_per_eu(2, 2))) void nf_policy_kernel(
    const float* __restrict__ x, const float* __restrict__ xs,
    const float* __restrict__ gW0, const float* __restrict__ gb0,
    const float* __restrict__ gW1, const float* __restrict__ gb1,
    const float* __restrict__ gW2, const float* __restrict__ gb2,
    float* __restrict__ out) {
  __shared__ __align__(16) f16x2 LW0[4096];  // [16p][4q][16m][4w] A-frags L1
  __shared__ __align__(16) f16x2 LW1[1024];  // [16p][2half][8row][4kk]
  __shared__ __align__(16) f16x2 LW2[4096];  // [16p][4b][16m][4kk(2 used)]
  __shared__ __align__(16) float LB0[256];   // [16p][16m]
  __shared__ __align__(16) float LB1[256];   // [16p][16m]
  __shared__ __align__(16) float LB2[1024];  // [16p][4b][16m]
  __shared__ __align__(16) float4 sHC[2048]; // [16p][128 active ln] H1H2 cache

  const int tid = threadIdx.x;
  // ---- stage weights: fp32 global -> f16 LDS in MFMA A-fragment order ----
  for (int i = tid; i < 4096; i += 256) {  // LW0
    const int p = i >> 8, rem = i & 255, qq = rem >> 6, rem2 = rem & 63;
    const int mm = rem2 >> 2, w = rem2 & 3;
    const int net = pbase(p) + (mm >> 3);
    const int h = mm & 7, k0 = qq * 8 + w * 2;
    const float* src = gW0 + net * 256 + h * 32 + k0;
    LW0[i] = pk(src[0], src[1]);
  }
  for (int i = tid; i < 1024; i += 256) {  // LW1
    const int p = i >> 6, rem = i & 63, half = rem >> 5;
    const int row = (rem >> 2) & 7, kk = rem & 3;
    const int net = pbase(p) + half;
    const float* src = gW1 + net * 64 + row * 8 + kk * 2;
    LW1[i] = pk(src[0], src[1]);
  }
  for (int i = tid; i < 4096; i += 256) {  // LW2 (rows permuted)
    const int p = i >> 8, rem = i & 255, b = rem >> 6, rem2 = rem & 63;
    const int mm = rem2 >> 2, kk = rem2 & 3;
    const int net = pbase(p) + (b >> 1);
    const int d = 8 * (mm >> 2) + ((b & 1) << 2) + (mm & 3);
    const float* src = gW2 + net * 256 + d * 8 + kk * 2;
    LW2[i] = pk(src[0], src[1]);
  }
  for (int i = tid; i < 256; i += 256) {  // LB0/LB1
    const int p = i >> 4, mm = i & 15;
    const int net = pbase(p) + (mm >> 3);
    LB0[i] = gb0[net * 8 + (mm & 7)];
    LB1[i] = gb1[net * 8 + (mm & 7)];
  }
  for (int i = tid; i < 1024; i += 256) {  // LB2 (permuted like LW2 rows)
    const int p = i >> 6, b = (i >> 4) & 3, mm = i & 15;
    const int net = pbase(p) + (b >> 1);
    const int d = 8 * (mm >> 2) + ((b & 1) << 2) + (mm & 3);
    LB2[i] = gb2[net * 32 + d];
  }
  __syncthreads();

  const int lane = tid & 63;
  const int wv = tid >> 6;
  const int n = lane & 15;   // MFMA col / A row role (lanes n>=8 mirror n-8)
  const int q = lane >> 4;   // quad: owns state dims 8q..8q+7
  const int e = blockIdx.x * 32 + wv * 8 + (n & 7);
  const int hcb = wv * 32 + q * 8 + (n & 7);  // compacted H-cache slot

  v4h z4;
#pragma unroll
  for (int jj = 0; jj < 4; ++jj) z4[jj] = (__fp16)0.f;
  const f32x4 zc = {0.f, 0.f, 0.f, 0.f};
  const bool act1 = (n < 8) == (q < 2);
  const int a1off = ((n & 7) << 2) + ((q & 1) << 1) + ((n >= 8) ? 32 : 0);
  const int abbase = n * 4 + ((q & 1) << 1);

  float lo[8], up[8], av[8], bv[8];
  {
    const float* xe = x + (size_t)e * 64;
    const float* se = xs + (size_t)e * 64;
    const float4 a0 = *(const float4*)(xe + q * 8);
    const float4 a1 = *(const float4*)(xe + q * 8 + 4);
    const float4 u0 = *(const float4*)(xe + 32 + q * 8);
    const float4 u1 = *(const float4*)(xe + 32 + q * 8 + 4);
    const float4 p0 = *(const float4*)(se + q * 8);
    const float4 p1 = *(const float4*)(se + q * 8 + 4);
    const float4 r0 = *(const float4*)(se + 32 + q * 8);
    const float4 r1 = *(const float4*)(se + 32 + q * 8 + 4);
    lo[0] = a0.x; lo[1] = a0.y; lo[2] = a0.z; lo[3] = a0.w;
    lo[4] = a1.x; lo[5] = a1.y; lo[6] = a1.z; lo[7] = a1.w;
    up[0] = u0.x; up[1] = u0.y; up[2] = u0.z; up[3] = u0.w;
    up[4] = u1.x; up[5] = u1.y; up[6] = u1.z; up[7] = u1.w;
    av[0] = -2.f * (a0.x - p0.x); av[1] = -2.f * (a0.y - p0.y);
    av[2] = -2.f * (a0.z - p0.z); av[3] = -2.f * (a0.w - p0.w);
    av[4] = -2.f * (a1.x - p1.x); av[5] = -2.f * (a1.y - p1.y);
    av[6] = -2.f * (a1.z - p1.z); av[7] = -2.f * (a1.w - p1.w);
    bv[0] = -2.f * (u0.x - r0.x); bv[1] = -2.f * (u0.y - r0.y);
    bv[2] = -2.f * (u0.z - r0.z); bv[3] = -2.f * (u0.w - r0.w);
    bv[4] = -2.f * (u1.x - r1.x); bv[5] = -2.f * (u1.y - r1.y);
    bv[6] = -2.f * (u1.z - r1.z); bv[7] = -2.f * (u1.w - r1.w);
  }

  float t8[8], s8[8], ut8[8], us8[8];

  // ---------------- forward: z = phi(x); cache H1/H2 frags ---------------
#pragma unroll
  for (int hs = 0; hs < 16; ++hs) {
    const int p = hs;
    float* v = (p & 1) ? up : lo;       // input state of this pair
    float* w = (p & 1) ? lo : up;       // state being updated
    U8 B;
    B.h[0] = pk(v[0], v[1]);
    B.h[1] = pk(v[2], v[3]);
    B.h[2] = pk(v[4], v[5]);
    B.h[3] = pk(v[6], v[7]);
    const v8h A0 = *(const v8h*)(LW0 + ((p * 64 + q * 16 + n) << 2));
    const f32x4 c0 = *(const f32x4*)(LB0 + p * 16 + q * 4);
    f32x4 d1 = __builtin_amdgcn_mfma_f32_16x16x32_f16(A0, B.v, c0, 0, 0, 0);
    float h1[4];
#pragma unroll
    for (int r = 0; r < 4; ++r) h1[r] = ftanh(d1[r]);
    U4 H1;
    H1.h[0] = pk(h1[0], h1[1]);
    H1.h[1] = pk(h1[2], h1[3]);
    v4h A1 = *(const v4h*)(LW1 + (p * 64 + a1off));
    A1 = act1 ? A1 : z4;
    const f32x4 c1 = *(const f32x4*)(LB1 + p * 16 + q * 4);
    f32x4 d2 = __builtin_amdgcn_mfma_f32_16x16x16f16(A1, H1.v, c1, 0, 0, 0);
    float h2[4];
#pragma unroll
    for (int r = 0; r < 4; ++r) h2[r] = ftanh(d2[r]);
    U4 H2;
    H2.h[0] = pk(h2[0], h2[1]);
    H2.h[1] = pk(h2[2], h2[3]);
    // cache both fragments (one b128 store; active lanes only, mirrors skip)
    {
      float4 pkd;
      pkd.x = __builtin_bit_cast(float, H1.h[0]);
      pkd.y = __builtin_bit_cast(float, H1.h[1]);
      pkd.z = __builtin_bit_cast(float, H2.h[0]);
      pkd.w = __builtin_bit_cast(float, H2.h[1]);
      if (n < 8) sHC[p * 128 + hcb] = pkd;
    }
#pragma unroll
    for (int b = 0; b < 4; ++b) {
      const bool act = (b < 2) == (q < 2);
      v4h Ab = *(const v4h*)(LW2 + (p * 256 + b * 64 + abbase));
      Ab = act ? Ab : z4;
      const f32x4 cb = *(const f32x4*)(LB2 + (p * 4 + b) * 16 + q * 4);
      f32x4 ob = __builtin_amdgcn_mfma_f32_16x16x16f16(Ab, H2.v, cb, 0, 0, 0);
      float* dst = (b < 2) ? t8 : s8;
      const int off = (b & 1) * 4;
#pragma unroll
      for (int r = 0; r < 4; ++r) dst[off + r] = ob[r];
    }
#pragma unroll
    for (int j = 0; j < 8; ++j) w[j] = fmaf(w[j], __expf(s8[j]), t8[j]);
  }

  // ------------- backward: y = J^{-1} g, inverting the flow -------------
#pragma unroll
  for (int hs = 15; hs >= 0; --hs) {
    const int p = hs;
    float* st = (p & 1) ? lo : up;      // state updated by this pair in fwd
    float* dme = (p & 1) ? av : bv;     // dual of that state
    float* dot = (p & 1) ? bv : av;     // dual of the pair's input state
    // cached fragments (mirror lanes read their twin's identical slot)
    U4 H1, H2;
    {
      const float4 pkd = sHC[p * 128 + hcb];
      H1.h[0] = __builtin_bit_cast(f16x2, pkd.x);
      H1.h[1] = __builtin_bit_cast(f16x2, pkd.y);
      H2.h[0] = __builtin_bit_cast(f16x2, pkd.z);
      H2.h[1] = __builtin_bit_cast(f16x2, pkd.w);
    }
    // JVP at the dual of the input state
    U8 Bu;
    Bu.h[0] = pk(dot[0], dot[1]);
    Bu.h[1] = pk(dot[2], dot[3]);
    Bu.h[2] = pk(dot[4], dot[5]);
    Bu.h[3] = pk(dot[6], dot[7]);
    const v8h A0 = *(const v8h*)(LW0 + ((p * 64 + q * 16 + n) << 2));
    f32x4 d1u = __builtin_amdgcn_mfma_f32_16x16x32_f16(A0, Bu.v, zc, 0, 0, 0);
    float g1[4];
#pragma unroll
    for (int r = 0; r < 4; ++r) {
      const float h1r = (float)H1.v[r];
      g1[r] = (1.f - h1r * h1r) * d1u[r];
    }
    U4 G1;
    G1.h[0] = pk(g1[0], g1[1]);
    G1.h[1] = pk(g1[2], g1[3]);
    v4h A1 = *(const v4h*)(LW1 + (p * 64 + a1off));
    A1 = act1 ? A1 : z4;
    f32x4 d2u = __builtin_amdgcn_mfma_f32_16x16x16f16(A1, G1.v, zc, 0, 0, 0);
    float g2[4];
#pragma unroll
    for (int r = 0; r < 4; ++r) {
      const float h2r = (float)H2.v[r];
      g2[r] = (1.f - h2r * h2r) * d2u[r];
    }
    U4 G2;
    G2.h[0] = pk(g2[0], g2[1]);
    G2.h[1] = pk(g2[2], g2[3]);
    // L3: t/s recompute (cached H2) + JVP, 8 independent MFMAs
#pragma unroll
    for (int b = 0; b < 4; ++b) {
      const bool act = (b < 2) == (q < 2);
      v4h Ab = *(const v4h*)(LW2 + (p * 256 + b * 64 + abbase));
      Ab = act ? Ab : z4;
      const f32x4 cb = *(const f32x4*)(LB2 + (p * 4 + b) * 16 + q * 4);
      f32x4 ob = __builtin_amdgcn_mfma_f32_16x16x16f16(Ab, H2.v, cb, 0, 0, 0);
      f32x4 jb = __builtin_amdgcn_mfma_f32_16x16x16f16(Ab, G2.v, zc, 0, 0, 0);
      float* dst = (b < 2) ? t8 : s8;
      float* jdst = (b < 2) ? ut8 : us8;
      const int off = (b & 1) * 4;
#pragma unroll
      for (int r = 0; r < 4; ++r) {
        dst[off + r] = ob[r];
        jdst[off + r] = jb[r];
      }
    }
    // invert coupling + dual update
#pragma unroll
    for (int j = 0; j < 8; ++j) {
      const float esi = __expf(-s8[j]);
      const float d = st[j] - t8[j];
      st[j] = d * esi;
      dme[j] = (dme[j] - ut8[j] - d * us8[j]) * esi;
    }
  }

  if (n < 8) {
    float* oe = out + (size_t)e * 64;
    float4 v;
    v.x = av[0]; v.y = av[1]; v.z = av[2]; v.w = av[3];
    *(float4*)(oe + q * 8) = v;
    v.x = av[4]; v.y = av[5]; v.z = av[6]; v.w = av[7];
    *(float4*)(oe + q * 8 + 4) = v;
    v.x = bv[0]; v.y = bv[1]; v.z = bv[2]; v.w = bv[3];
    *(float4*)(oe + 32 + q * 8) = v;
    v.x = bv[4]; v.y = bv[5]; v.z = bv[6]; v.w = bv[7];
    *(float4*)(oe + 32 + q * 8 + 4) = v;
  }
}

extern "C" void kernel_launch(void* const* d_in, const int* in_sizes, int n_in,
                              void* d_out, int out_size, void* d_ws,
                              size_t ws_size, hipStream_t stream) {
  const float* x  = (const float*)d_in[0];
  const float* xs = (const float*)d_in[1];
  const float* W0 = (const float*)d_in[2];
  const float* b0 = (const float*)d_in[3];
  const float* W1 = (const float*)d_in[4];
  const float* b1 = (const float*)d_in[5];
  const float* W2 = (const float*)d_in[6];
  const float* b2 = (const float*)d_in[7];
  float* out = (float*)d_out;

  dim3 grid(NB / 32);  // 512 blocks, 32 elements each (8 per wave, mirrored)
  dim3 block(256);
  nf_policy_kernel<<<grid, block, 0, stream>>>(x, xs, W0, b0, W1, b1, W2, b2,
                                               out);
}

// Round 4
// 103.736 us; speedup vs baseline: 1.0523x; 1.0288x over previous
//
#include <hip/hip_runtime.h>

// B=16384, DIM=64, 8 coupling steps, H=8, D2=32.
// y = J^{-1} g applied analytically (triangular coupling blocks -> MLP JVPs);
// intermediate states recovered by inverting the flow from z = phi(x).
//
// R14 = R13 with the SCRATCH ROOT CAUSE fixed. R13 proved the ~28 MB phantom
// WRITE_SIZE is NOT register spilling: waves_per_eu(2,2) granted a 256-VGPR
// budget yet VGPR_Count stayed 128 and the traffic persisted. The state
// arrays (lo/up/av/bv, t8/s8/ut8/us8) were accessed through conditional
// pointers (float* v = (p&1) ? up : lo), which defeats SROA (it runs before
// unrolling folds the selects) -> allocas -> scratch on the serial chain.
// R14 expands fwd/bwd half-steps via macros taking the arrays BY NAME and
// unrolls the L3 b-loop into four direct-destination blocks: constant
// indices only, no pointer into any local array ever formed.
// Layout identity (gfx950, verified m89): D (col=lane&15,row=4q+reg) ==
// B-operand (n=lane&15,k=4q+j) for K=16 -> tanh(D)->pack is per-lane, zero
// cross-lane ops.

namespace {

typedef __fp16 f16x2 __attribute__((ext_vector_type(2)));
typedef __fp16 v4h __attribute__((ext_vector_type(4)));
typedef __fp16 v8h __attribute__((ext_vector_type(8)));
typedef float f32x4 __attribute__((ext_vector_type(4)));

constexpr int NB = 16384;

__device__ __forceinline__ float frcp(float x) { return __builtin_amdgcn_rcpf(x); }
__device__ __forceinline__ float ftanh(float x) {
  float e = __expf(2.f * x);
  return 1.f - 2.f * frcp(e + 1.f);
}
__device__ __forceinline__ f16x2 pk(float a, float b) {
  return __builtin_amdgcn_cvt_pkrtz(a, b);
}

union U8 { v8h v; f16x2 h[4]; float4 f4; };
union U4 { v4h v; f16x2 h[2]; float2 f2; };

// net pair p (0..15): step i = p>>1, half = p&1 -> t-net base.
__device__ __forceinline__ int pbase(int p) {
  return ((p >> 1) << 2) + ((p & 1) << 1);
}

}  // namespace

// ---- forward L3 block: one of four output quads, direct destination ----
#define L3_FWD(P, BB, DST, OFF)                                               \
  do {                                                                        \
    const bool act_ = ((BB) < 2) == (q < 2);                                  \
    v4h Ab = *(const v4h*)(LW2 + ((P)*256 + (BB)*64 + abbase));               \
    Ab = act_ ? Ab : z4;                                                      \
    const f32x4 cb = *(const f32x4*)(LB2 + ((P)*4 + (BB)) * 16 + q * 4);      \
    f32x4 ob = __builtin_amdgcn_mfma_f32_16x16x16f16(Ab, H2.v, cb, 0, 0, 0);  \
    DST[(OFF) + 0] = ob[0];                                                   \
    DST[(OFF) + 1] = ob[1];                                                   \
    DST[(OFF) + 2] = ob[2];                                                   \
    DST[(OFF) + 3] = ob[3];                                                   \
  } while (0)

// ---- forward half-step P: reads V[8] (by name), updates W[8] (by name) ----
#define FWD_HALF(P, V, W)                                                     \
  do {                                                                        \
    U8 Bq;                                                                    \
    Bq.h[0] = pk(V[0], V[1]);                                                 \
    Bq.h[1] = pk(V[2], V[3]);                                                 \
    Bq.h[2] = pk(V[4], V[5]);                                                 \
    Bq.h[3] = pk(V[6], V[7]);                                                 \
    const v8h A0 = *(const v8h*)(LW0 + (((P)*64 + q * 16 + n) << 2));         \
    const f32x4 c0 = *(const f32x4*)(LB0 + (P)*16 + q * 4);                   \
    f32x4 d1 = __builtin_amdgcn_mfma_f32_16x16x32_f16(A0, Bq.v, c0, 0, 0, 0); \
    U4 H1;                                                                    \
    H1.h[0] = pk(ftanh(d1[0]), ftanh(d1[1]));                                 \
    H1.h[1] = pk(ftanh(d1[2]), ftanh(d1[3]));                                 \
    v4h A1 = *(const v4h*)(LW1 + ((P)*64 + a1off));                           \
    A1 = act1 ? A1 : z4;                                                      \
    const f32x4 c1 = *(const f32x4*)(LB1 + (P)*16 + q * 4);                   \
    f32x4 d2 = __builtin_amdgcn_mfma_f32_16x16x16f16(A1, H1.v, c1, 0, 0, 0);  \
    U4 H2;                                                                    \
    H2.h[0] = pk(ftanh(d2[0]), ftanh(d2[1]));                                 \
    H2.h[1] = pk(ftanh(d2[2]), ftanh(d2[3]));                                 \
    if (n < 8) {                                                              \
      float4 pkd;                                                             \
      pkd.x = __builtin_bit_cast(float, H1.h[0]);                             \
      pkd.y = __builtin_bit_cast(float, H1.h[1]);                             \
      pkd.z = __builtin_bit_cast(float, H2.h[0]);                             \
      pkd.w = __builtin_bit_cast(float, H2.h[1]);                             \
      sHC[(P)*128 + hcb] = pkd;                                               \
    }                                                                         \
    float t8[8], s8[8];                                                       \
    L3_FWD(P, 0, t8, 0);                                                      \
    L3_FWD(P, 1, t8, 4);                                                      \
    L3_FWD(P, 2, s8, 0);                                                      \
    L3_FWD(P, 3, s8, 4);                                                      \
    _Pragma("unroll") for (int j = 0; j < 8; ++j)                             \
        W[j] = fmaf(W[j], __expf(s8[j]), t8[j]);                              \
  } while (0)

// ---- backward L3 block: t/s recompute + JVP, direct destinations ----
#define L3_BWD(P, BB, DST, JDST, OFF)                                         \
  do {                                                                        \
    const bool act_ = ((BB) < 2) == (q < 2);                                  \
    v4h Ab = *(const v4h*)(LW2 + ((P)*256 + (BB)*64 + abbase));               \
    Ab = act_ ? Ab : z4;                                                      \
    const f32x4 cb = *(const f32x4*)(LB2 + ((P)*4 + (BB)) * 16 + q * 4);      \
    f32x4 ob = __builtin_amdgcn_mfma_f32_16x16x16f16(Ab, H2.v, cb, 0, 0, 0);  \
    f32x4 jb = __builtin_amdgcn_mfma_f32_16x16x16f16(Ab, G2.v, zc, 0, 0, 0);  \
    DST[(OFF) + 0] = ob[0];                                                   \
    DST[(OFF) + 1] = ob[1];                                                   \
    DST[(OFF) + 2] = ob[2];                                                   \
    DST[(OFF) + 3] = ob[3];                                                   \
    JDST[(OFF) + 0] = jb[0];                                                  \
    JDST[(OFF) + 1] = jb[1];                                                  \
    JDST[(OFF) + 2] = jb[2];                                                  \
    JDST[(OFF) + 3] = jb[3];                                                  \
  } while (0)

// ---- backward half-step P: inverts state ST, updates duals DME from DOT ----
#define BWD_HALF(P, ST, DME, DOT)                                             \
  do {                                                                        \
    U4 H1, H2;                                                                \
    {                                                                         \
      const float4 pkd = sHC[(P)*128 + hcb];                                  \
      H1.h[0] = __builtin_bit_cast(f16x2, pkd.x);                             \
      H1.h[1] = __builtin_bit_cast(f16x2, pkd.y);                             \
      H2.h[0] = __builtin_bit_cast(f16x2, pkd.z);                             \
      H2.h[1] = __builtin_bit_cast(f16x2, pkd.w);                             \
    }                                                                         \
    U8 Bu;                                                                    \
    Bu.h[0] = pk(DOT[0], DOT[1]);                                             \
    Bu.h[1] = pk(DOT[2], DOT[3]);                                             \
    Bu.h[2] = pk(DOT[4], DOT[5]);                                             \
    Bu.h[3] = pk(DOT[6], DOT[7]);                                             \
    const v8h A0 = *(const v8h*)(LW0 + (((P)*64 + q * 16 + n) << 2));         \
    f32x4 d1u = __builtin_amdgcn_mfma_f32_16x16x32_f16(A0, Bu.v, zc, 0, 0, 0);\
    U4 G1;                                                                    \
    {                                                                         \
      const float ha = (float)H1.v[0], hb = (float)H1.v[1];                   \
      const float hc = (float)H1.v[2], hd = (float)H1.v[3];                   \
      G1.h[0] = pk((1.f - ha * ha) * d1u[0], (1.f - hb * hb) * d1u[1]);       \
      G1.h[1] = pk((1.f - hc * hc) * d1u[2], (1.f - hd * hd) * d1u[3]);       \
    }                                                                         \
    v4h A1 = *(const v4h*)(LW1 + ((P)*64 + a1off));                           \
    A1 = act1 ? A1 : z4;                                                      \
    f32x4 d2u = __builtin_amdgcn_mfma_f32_16x16x16f16(A1, G1.v, zc, 0, 0, 0); \
    U4 G2;                                                                    \
    {                                                                         \
      const float ha = (float)H2.v[0], hb = (float)H2.v[1];                   \
      const float hc = (float)H2.v[2], hd = (float)H2.v[3];                   \
      G2.h[0] = pk((1.f - ha * ha) * d2u[0], (1.f - hb * hb) * d2u[1]);       \
      G2.h[1] = pk((1.f - hc * hc) * d2u[2], (1.f - hd * hd) * d2u[3]);       \
    }                                                                         \
    float t8[8], s8[8], ut8[8], us8[8];                                       \
    L3_BWD(P, 0, t8, ut8, 0);                                                 \
    L3_BWD(P, 1, t8, ut8, 4);                                                 \
    L3_BWD(P, 2, s8, us8, 0);                                                 \
    L3_BWD(P, 3, s8, us8, 4);                                                 \
    _Pragma("unroll") for (int j = 0; j < 8; ++j) {                           \
      const float esi = __expf(-s8[j]);                                       \
      const float d = ST[j] - t8[j];                                          \
      ST[j] = d * esi;                                                        \
      DME[j] = (DME[j] - ut8[j] - d * us8[j]) * esi;                          \
    }                                                                         \
  } while (0)

// 256 threads = 4 waves = 32 elements/block (8/wave, mirrored), grid 512 ->
// 2048 waves = 2/SIMD, 2 blocks/CU. LDS: 42 KiB weights + 32 KiB H-cache =
// 74 KiB (<80 KiB so two blocks co-reside). waves_per_eu pinned (2,2): VGPR
// budget 256 (the LDS-implied occupancy), no chasing 4 waves/EU.
__global__ __attribute__((amdgpu_flat_work_group_size(256, 256),
                          amdgpu_waves_per_eu(2, 2))) void nf_policy_kernel(
    const float* __restrict__ x, const float* __restrict__ xs,
    const float* __restrict__ gW0, const float* __restrict__ gb0,
    const float* __restrict__ gW1, const float* __restrict__ gb1,
    const float* __restrict__ gW2, const float* __restrict__ gb2,
    float* __restrict__ out) {
  __shared__ __align__(16) f16x2 LW0[4096];  // [16p][4q][16m][4w] A-frags L1
  __shared__ __align__(16) f16x2 LW1[1024];  // [16p][2half][8row][4kk]
  __shared__ __align__(16) f16x2 LW2[4096];  // [16p][4b][16m][4kk(2 used)]
  __shared__ __align__(16) float LB0[256];   // [16p][16m]
  __shared__ __align__(16) float LB1[256];   // [16p][16m]
  __shared__ __align__(16) float LB2[1024];  // [16p][4b][16m]
  __shared__ __align__(16) float4 sHC[2048]; // [16p][128 active ln] H1H2 cache

  const int tid = threadIdx.x;
  // ---- stage weights: fp32 global -> f16 LDS in MFMA A-fragment order ----
  for (int i = tid; i < 4096; i += 256) {  // LW0
    const int p = i >> 8, rem = i & 255, qq = rem >> 6, rem2 = rem & 63;
    const int mm = rem2 >> 2, w = rem2 & 3;
    const int net = pbase(p) + (mm >> 3);
    const int h = mm & 7, k0 = qq * 8 + w * 2;
    const float* src = gW0 + net * 256 + h * 32 + k0;
    LW0[i] = pk(src[0], src[1]);
  }
  for (int i = tid; i < 1024; i += 256) {  // LW1
    const int p = i >> 6, rem = i & 63, half = rem >> 5;
    const int row = (rem >> 2) & 7, kk = rem & 3;
    const int net = pbase(p) + half;
    const float* src = gW1 + net * 64 + row * 8 + kk * 2;
    LW1[i] = pk(src[0], src[1]);
  }
  for (int i = tid; i < 4096; i += 256) {  // LW2 (rows permuted)
    const int p = i >> 8, rem = i & 255, b = rem >> 6, rem2 = rem & 63;
    const int mm = rem2 >> 2, kk = rem2 & 3;
    const int net = pbase(p) + (b >> 1);
    const int d = 8 * (mm >> 2) + ((b & 1) << 2) + (mm & 3);
    const float* src = gW2 + net * 256 + d * 8 + kk * 2;
    LW2[i] = pk(src[0], src[1]);
  }
  for (int i = tid; i < 256; i += 256) {  // LB0/LB1
    const int p = i >> 4, mm = i & 15;
    const int net = pbase(p) + (mm >> 3);
    LB0[i] = gb0[net * 8 + (mm & 7)];
    LB1[i] = gb1[net * 8 + (mm & 7)];
  }
  for (int i = tid; i < 1024; i += 256) {  // LB2 (permuted like LW2 rows)
    const int p = i >> 6, b = (i >> 4) & 3, mm = i & 15;
    const int net = pbase(p) + (b >> 1);
    const int d = 8 * (mm >> 2) + ((b & 1) << 2) + (mm & 3);
    LB2[i] = gb2[net * 32 + d];
  }
  __syncthreads();

  const int lane = tid & 63;
  const int wv = tid >> 6;
  const int n = lane & 15;   // MFMA col / A row role (lanes n>=8 mirror n-8)
  const int q = lane >> 4;   // quad: owns state dims 8q..8q+7
  const int e = blockIdx.x * 32 + wv * 8 + (n & 7);
  const int hcb = wv * 32 + q * 8 + (n & 7);  // compacted H-cache slot

  v4h z4;
#pragma unroll
  for (int jj = 0; jj < 4; ++jj) z4[jj] = (__fp16)0.f;
  const f32x4 zc = {0.f, 0.f, 0.f, 0.f};
  const bool act1 = (n < 8) == (q < 2);
  const int a1off = ((n & 7) << 2) + ((q & 1) << 1) + ((n >= 8) ? 32 : 0);
  const int abbase = n * 4 + ((q & 1) << 1);

  float lo[8], up[8], av[8], bv[8];
  {
    const float* xe = x + (size_t)e * 64;
    const float* se = xs + (size_t)e * 64;
    const float4 a0 = *(const float4*)(xe + q * 8);
    const float4 a1 = *(const float4*)(xe + q * 8 + 4);
    const float4 u0 = *(const float4*)(xe + 32 + q * 8);
    const float4 u1 = *(const float4*)(xe + 32 + q * 8 + 4);
    const float4 p0 = *(const float4*)(se + q * 8);
    const float4 p1 = *(const float4*)(se + q * 8 + 4);
    const float4 r0 = *(const float4*)(se + 32 + q * 8);
    const float4 r1 = *(const float4*)(se + 32 + q * 8 + 4);
    lo[0] = a0.x; lo[1] = a0.y; lo[2] = a0.z; lo[3] = a0.w;
    lo[4] = a1.x; lo[5] = a1.y; lo[6] = a1.z; lo[7] = a1.w;
    up[0] = u0.x; up[1] = u0.y; up[2] = u0.z; up[3] = u0.w;
    up[4] = u1.x; up[5] = u1.y; up[6] = u1.z; up[7] = u1.w;
    av[0] = -2.f * (a0.x - p0.x); av[1] = -2.f * (a0.y - p0.y);
    av[2] = -2.f * (a0.z - p0.z); av[3] = -2.f * (a0.w - p0.w);
    av[4] = -2.f * (a1.x - p1.x); av[5] = -2.f * (a1.y - p1.y);
    av[6] = -2.f * (a1.z - p1.z); av[7] = -2.f * (a1.w - p1.w);
    bv[0] = -2.f * (u0.x - r0.x); bv[1] = -2.f * (u0.y - r0.y);
    bv[2] = -2.f * (u0.z - r0.z); bv[3] = -2.f * (u0.w - r0.w);
    bv[4] = -2.f * (u1.x - r1.x); bv[5] = -2.f * (u1.y - r1.y);
    bv[6] = -2.f * (u1.z - r1.z); bv[7] = -2.f * (u1.w - r1.w);
  }

  // ---------------- forward: z = phi(x); cache H1/H2 frags ---------------
  // even p: reads lo, updates up; odd p: reads up, updates lo.
#pragma unroll
  for (int st = 0; st < 8; ++st) {
    FWD_HALF(2 * st, lo, up);
    FWD_HALF(2 * st + 1, up, lo);
  }

  // ------------- backward: y = J^{-1} g, inverting the flow -------------
  // odd p first (it updated lo in fwd; its input dual is bv), then even p.
#pragma unroll
  for (int st = 7; st >= 0; --st) {
    BWD_HALF(2 * st + 1, lo, av, bv);
    BWD_HALF(2 * st, up, bv, av);
  }

  if (n < 8) {
    float* oe = out + (size_t)e * 64;
    float4 v;
    v.x = av[0]; v.y = av[1]; v.z = av[2]; v.w = av[3];
    *(float4*)(oe + q * 8) = v;
    v.x = av[4]; v.y = av[5]; v.z = av[6]; v.w = av[7];
    *(float4*)(oe + q * 8 + 4) = v;
    v.x = bv[0]; v.y = bv[1]; v.z = bv[2]; v.w = bv[3];
    *(float4*)(oe + 32 + q * 8) = v;
    v.x = bv[4]; v.y = bv[5]; v.z = bv[6]; v.w = bv[7];
    *(float4*)(oe + 32 + q * 8 + 4) = v;
  }
}

extern "C" void kernel_launch(void* const* d_in, const int* in_sizes, int n_in,
                              void* d_out, int out_size, void* d_ws,
                              size_t ws_size, hipStream_t stream) {
  const float* x  = (const float*)d_in[0];
  const float* xs = (const float*)d_in[1];
  const float* W0 = (const float*)d_in[2];
  const float* b0 = (const float*)d_in[3];
  const float* W1 = (const float*)d_in[4];
  const float* b1 = (const float*)d_in[5];
  const float* W2 = (const float*)d_in[6];
  const float* b2 = (const float*)d_in[7];
  float* out = (float*)d_out;

  dim3 grid(NB / 32);  // 512 blocks, 32 elements each (8 per wave, mirrored)
  dim3 block(256);
  nf_policy_kernel<<<grid, block, 0, stream>>>(x, xs, W0, b0, W1, b1, W2, b2,
                                               out);
}